// Round 1
// baseline (336.424 us; speedup 1.0000x reference)
//
#include <hip/hip_runtime.h>
#include <hip/hip_bf16.h>

#define TT 128
#define BB 512
#define DD 500
#define NVOCAB 1000
#define NV4 125   // DD floats = 125 float4 (2000 B, always 16B-aligned per row)

// ---------------------------------------------------------------------------
// Kernel 1: per-column greedy packer metadata.
// One thread per batch column b. Sequential over T=128 tokens.
// Boundary decision for the PENDING valid token is made when the NEXT valid
// token arrives (nxt_after == its length); end-of-column == nxt_after BIG ->
// always a boundary. Emits per-segment inclusive t-ranges [lo, hi] and
// new_lengths[b] (= #segments).
// ---------------------------------------------------------------------------
__global__ void meta_kernel(const int* __restrict__ src,
                            const int* __restrict__ token_lengths,
                            const int* __restrict__ token_len_p,
                            int* __restrict__ seg_lo,
                            int* __restrict__ seg_hi,
                            int* __restrict__ new_len) {
    __shared__ int tl[NVOCAB];
    for (int i = threadIdx.x; i < NVOCAB; i += blockDim.x) tl[i] = token_lengths[i];
    __syncthreads();

    int b = blockIdx.x * blockDim.x + threadIdx.x;
    if (b >= BB) return;

    // token_len arrives as a 1-element array; guard against it being f32 bits.
    int bits = token_len_p[0];
    int token_len = bits;
    if (bits > 1000000 || bits <= 0) token_len = (int)__int_as_float(bits);

    int curr = 0, seg = 0, lo = 0, pend_t = -1;
    for (int t = 0; t < TT; ++t) {
        int s = src[t * BB + b];
        if (s == 1) continue;                 // pad token: invalid
        int l = (s == 0) ? 4 : tl[s];
        if (pend_t >= 0 && curr + l > token_len) {
            // boundary at pend_t (reference: curr + nxt_after > token_len)
            seg_lo[seg * BB + b] = lo;
            seg_hi[seg * BB + b] = pend_t;
            lo = pend_t + 1;
            curr = 0;
            seg++;
        }
        curr += l;
        pend_t = t;
    }
    if (pend_t >= 0) {                        // nxt_after == BIG -> boundary
        seg_lo[seg * BB + b] = lo;
        seg_hi[seg * BB + b] = pend_t;
        seg++;
    }
    new_len[b] = seg;
}

// ---------------------------------------------------------------------------
// Kernel 2: stable descending argsort of new_len (B=512) by rank-counting,
// one block of 512 threads. Also writes merged_lengths (as float) into the
// tail of d_out.
// ---------------------------------------------------------------------------
__global__ void sort_kernel(const int* __restrict__ new_len,
                            int* __restrict__ order,
                            float* __restrict__ out_len) {
    __shared__ int lens[BB];
    __shared__ int ord[BB];
    int j = threadIdx.x;
    lens[j] = new_len[j];
    __syncthreads();
    int lj = lens[j];
    int rank = 0;
    #pragma unroll 8
    for (int i = 0; i < BB; ++i) {
        int li = lens[i];
        rank += (int)((li > lj) || (li == lj && i < j));
    }
    ord[rank] = j;
    __syncthreads();
    order[j] = ord[j];
    out_len[j] = (float)lens[ord[j]];
}

// ---------------------------------------------------------------------------
// Kernel 3: gather. One block per output row (r, j); b = order[j].
// r <  n_b : sum valid embedded rows over segment r's [lo,hi] (t-order => same
//            fp summation order as the reference scan).
// r >= n_b : identity copy of embedded[r, b, :].
// 128 threads; thread i owns float4 #i of the 125 per row.
// ---------------------------------------------------------------------------
__global__ void __launch_bounds__(128)
gather_kernel(const float* __restrict__ emb,
              const int* __restrict__ src,
              const int* __restrict__ seg_lo,
              const int* __restrict__ seg_hi,
              const int* __restrict__ new_len,
              const int* __restrict__ order,
              float* __restrict__ out) {
    int idx = blockIdx.x;           // idx = r*BB + j
    int r = idx >> 9;               // BB = 512
    int j = idx & (BB - 1);
    int b = order[j];
    int n = new_len[b];
    int tid = threadIdx.x;

    float4* obase = (float4*)(out + (size_t)idx * DD);

    if (r >= n) {
        const float4* e = (const float4*)(emb + ((size_t)r * BB + b) * DD);
        if (tid < NV4) obase[tid] = e[tid];
    } else {
        int lo = seg_lo[r * BB + b];
        int hi = seg_hi[r * BB + b];
        float4 acc = make_float4(0.f, 0.f, 0.f, 0.f);
        for (int t = lo; t <= hi; ++t) {
            if (src[t * BB + b] != 1) {
                const float4* e = (const float4*)(emb + ((size_t)t * BB + b) * DD);
                if (tid < NV4) {
                    float4 v = e[tid];
                    acc.x += v.x; acc.y += v.y; acc.z += v.z; acc.w += v.w;
                }
            }
        }
        if (tid < NV4) obase[tid] = acc;
    }
}

extern "C" void kernel_launch(void* const* d_in, const int* in_sizes, int n_in,
                              void* d_out, int out_size, void* d_ws, size_t ws_size,
                              hipStream_t stream) {
    const float* embedded      = (const float*)d_in[0];
    const int*   src           = (const int*)d_in[1];
    // d_in[2] = lengths (unused by the reference computation)
    const int*   token_lengths = (const int*)d_in[3];
    const int*   token_len_p   = (const int*)d_in[4];

    float* out = (float*)d_out;                       // T*B*D packed + B lengths

    int* seg_lo  = (int*)d_ws;                        // T*B
    int* seg_hi  = seg_lo + TT * BB;                  // T*B
    int* new_len = seg_hi + TT * BB;                  // B
    int* order   = new_len + BB;                      // B

    meta_kernel<<<2, 256, 0, stream>>>(src, token_lengths, token_len_p,
                                       seg_lo, seg_hi, new_len);
    sort_kernel<<<1, BB, 0, stream>>>(new_len, order, out + (size_t)TT * BB * DD);
    gather_kernel<<<TT * BB, 128, 0, stream>>>(embedded, src, seg_lo, seg_hi,
                                               new_len, order, out);
}

// Round 2
// 305.592 us; speedup vs baseline: 1.1009x; 1.1009x over previous
//
#include <hip/hip_runtime.h>
#include <hip/hip_bf16.h>

#define TT 128
#define BB 512
#define DD 500
#define NVOCAB 1000
#define NV4 125   // DD floats = 125 float4 per row (2000 B, 16B-aligned)

// ---------------------------------------------------------------------------
// Workspace layout (ws 16B-aligned):
//   mask    : ulonglong2[BB]        (16 B/col, 128-bit valid mask)     8 KB
//   desc    : int[TT*BB]            (packed per-output-row descriptor) 256 KB
//   new_len : int[BB]                                                  2 KB
//   lohi    : unsigned short[TT*BB] (lo | hi<<7 per segment)           128 KB
// ---------------------------------------------------------------------------

// Kernel 1: per-column greedy packer metadata. 8 blocks x 64 threads.
// Phase 1: stage src into LDS with 128 independent coalesced loads.
// Phase 2: sequential scan from LDS; emit packed [lo,hi] per segment,
//          per-column 128-bit valid mask, and new_len.
__global__ void __launch_bounds__(64)
meta_kernel(const int* __restrict__ src,
            const int* __restrict__ token_lengths,
            const int* __restrict__ token_len_p,
            unsigned short* __restrict__ lohi,
            int* __restrict__ new_len,
            ulonglong2* __restrict__ mask) {
    __shared__ int tl[NVOCAB];
    __shared__ int ssrc[TT * 64];

    int tid = threadIdx.x;
    for (int i = tid; i < NVOCAB; i += 64) tl[i] = token_lengths[i];

    int b = blockIdx.x * 64 + tid;
    // Phase 1: coalesced staging, all loads independent -> deep pipeline.
    #pragma unroll 8
    for (int t = 0; t < TT; ++t) ssrc[t * 64 + tid] = src[t * BB + b];
    __syncthreads();

    // token_len arrives as a 1-element int array; guard vs f32 bits.
    int bits = token_len_p[0];
    int token_len = bits;
    if (bits > 1000000 || bits <= 0) token_len = (int)__int_as_float(bits);

    int curr = 0, seg = 0, lo = 0, pend = -1;
    unsigned long long m0 = 0ull, m1 = 0ull;
    for (int t = 0; t < TT; ++t) {
        int s = ssrc[t * 64 + tid];
        if (s == 1) continue;                  // pad: invalid
        int l = (s == 0) ? 4 : tl[s];
        if (pend >= 0 && curr + l > token_len) {
            lohi[seg * BB + b] = (unsigned short)(lo | (pend << 7));
            lo = pend + 1; curr = 0; seg++;
        }
        curr += l; pend = t;
        if (t < 64) m0 |= 1ull << t; else m1 |= 1ull << (t - 64);
    }
    if (pend >= 0) {                           // final segment (nxt==BIG)
        lohi[seg * BB + b] = (unsigned short)(lo | (pend << 7));
        seg++;
    }
    new_len[b] = seg;
    mask[b] = make_ulonglong2(m0, m1);
}

// Kernel 2: stable descending argsort (rank-count) + merged_lengths output +
// per-output-row descriptor build. One block of 512 threads.
// desc[r*BB+j] = b | lo<<9 | hi<<16 | 1<<23  (packed row)   or   b (identity).
__global__ void __launch_bounds__(BB)
sort_desc_kernel(const int* __restrict__ new_len,
                 const unsigned short* __restrict__ lohi,
                 int* __restrict__ desc,
                 float* __restrict__ out_len) {
    __shared__ int lens[BB];
    __shared__ int ord[BB];
    int j = threadIdx.x;
    lens[j] = new_len[j];
    __syncthreads();
    int lj = lens[j];
    int rank = 0;
    #pragma unroll 8
    for (int i = 0; i < BB; ++i) {
        int li = lens[i];
        rank += (int)((li > lj) || (li == lj && i < j));
    }
    ord[rank] = j;
    __syncthreads();
    int b = ord[j];
    int n = lens[b];
    out_len[j] = (float)n;

    #pragma unroll 4
    for (int r = 0; r < TT; ++r) {
        int d = b;
        if (r < n) {
            int lh = (int)lohi[r * BB + b];
            d = b | ((lh & 127) << 9) | (((lh >> 7) & 127) << 16) | (1 << 23);
        }
        desc[r * BB + j] = d;      // coalesced store
    }
}

// Kernel 3: gather. 256 threads = 2 output rows per block; one desc load per
// row (wave-uniform), branchless masked-FMA sum over the segment.
__global__ void __launch_bounds__(256)
gather_kernel(const float* __restrict__ emb,
              const int* __restrict__ desc,
              const ulonglong2* __restrict__ mask,
              float* __restrict__ out) {
    int idx  = blockIdx.x * 2 + (threadIdx.x >> 7);   // output row r*BB+j
    int lane = threadIdx.x & 127;
    int d = desc[idx];
    int b = d & 511;
    if (lane >= NV4) return;

    float4* o = (float4*)(out + (size_t)idx * DD) + lane;

    if (!(d & (1 << 23))) {
        // identity row: out[r][j] = emb[r][b]
        int r = idx >> 9;
        *o = *((const float4*)(emb + ((size_t)r * BB + b) * DD) + lane);
    } else {
        int lo = (d >> 9) & 127;
        int hi = (d >> 16) & 127;
        ulonglong2 m = mask[b];
        float4 acc = make_float4(0.f, 0.f, 0.f, 0.f);
        for (int t = lo; t <= hi; ++t) {
            unsigned long long bit = (t < 64) ? (m.x >> t) : (m.y >> (t - 64));
            float w = (float)(bit & 1ull);
            float4 v = *((const float4*)(emb + ((size_t)t * BB + b) * DD) + lane);
            acc.x = fmaf(w, v.x, acc.x);
            acc.y = fmaf(w, v.y, acc.y);
            acc.z = fmaf(w, v.z, acc.z);
            acc.w = fmaf(w, v.w, acc.w);
        }
        *o = acc;
    }
}

extern "C" void kernel_launch(void* const* d_in, const int* in_sizes, int n_in,
                              void* d_out, int out_size, void* d_ws, size_t ws_size,
                              hipStream_t stream) {
    const float* embedded      = (const float*)d_in[0];
    const int*   src           = (const int*)d_in[1];
    // d_in[2] = lengths (unused by reference computation)
    const int*   token_lengths = (const int*)d_in[3];
    const int*   token_len_p   = (const int*)d_in[4];

    float* out = (float*)d_out;                 // T*B*D packed rows + B lengths

    ulonglong2*     mask    = (ulonglong2*)d_ws;                    // 8 KB
    int*            desc    = (int*)(mask + BB);                    // 256 KB
    int*            new_len = desc + TT * BB;                       // 2 KB
    unsigned short* lohi    = (unsigned short*)(new_len + BB);      // 128 KB

    meta_kernel<<<BB / 64, 64, 0, stream>>>(src, token_lengths, token_len_p,
                                            lohi, new_len, mask);
    sort_desc_kernel<<<1, BB, 0, stream>>>(new_len, lohi, desc,
                                           out + (size_t)TT * BB * DD);
    gather_kernel<<<TT * BB / 2, 256, 0, stream>>>(embedded, desc, mask, out);
}